// Round 2
// baseline (132873.364 us; speedup 1.0000x reference)
//
#include <hip/hip_runtime.h>
#include <math.h>

#define BATCH 32
#define SEQ   512
#define IDIM  256
#define RDIM  2048
#define ODIM  256
#define LEAK  0.3f

#define SCAN_BLOCKS  256
#define SCAN_THREADS 512
#define ROWS_PER_BLK 8   // RDIM / SCAN_BLOCKS

typedef float f4 __attribute__((ext_vector_type(4)));

// ---------------------------------------------------------------------------
// 8 L2-bypassing (agent-coherent, sc1) float4 loads, stride 256 B, one waitcnt.
// sc1 loads read directly from the device-coherent Infinity Cache - no
// buffer_inv needed, no stale per-XCD L2 lines possible.
// ---------------------------------------------------------------------------
__device__ __forceinline__ void load8_f4_sc1(const float* base, f4* r) {
    asm volatile(
        "global_load_dwordx4 %0, %8, off sc1\n\t"
        "global_load_dwordx4 %1, %8, off offset:256 sc1\n\t"
        "global_load_dwordx4 %2, %8, off offset:512 sc1\n\t"
        "global_load_dwordx4 %3, %8, off offset:768 sc1\n\t"
        "global_load_dwordx4 %4, %8, off offset:1024 sc1\n\t"
        "global_load_dwordx4 %5, %8, off offset:1280 sc1\n\t"
        "global_load_dwordx4 %6, %8, off offset:1536 sc1\n\t"
        "global_load_dwordx4 %7, %8, off offset:1792 sc1\n\t"
        "s_waitcnt vmcnt(0)"
        : "=v"(r[0]), "=v"(r[1]), "=v"(r[2]), "=v"(r[3]),
          "=v"(r[4]), "=v"(r[5]), "=v"(r[6]), "=v"(r[7])
        : "v"(base)
        : "memory");
}

// ---------------------------------------------------------------------------
// init: copy initial state into states slot 0, zero per-block flags
// ---------------------------------------------------------------------------
__global__ void esn_init(const float* __restrict__ s0, float* __restrict__ states,
                         unsigned* __restrict__ flags) {
    int idx = blockIdx.x * blockDim.x + threadIdx.x;
    const int n4 = (BATCH * RDIM) / 4;
    if (idx < n4) {
        ((float4*)states)[idx] = ((const float4*)s0)[idx];
    }
    if (idx < SCAN_BLOCKS) flags[idx] = 0u;
}

// ---------------------------------------------------------------------------
// persistent cooperative scan kernel - fence-free sc1 exchange
// grid 256 x 512. Block owns rows [r0, r0+8) of W, resident in LDS.
// wave w handles batches 4w..4w+3; lane: bb = lane&3, ks = lane>>2
// ---------------------------------------------------------------------------
__global__ __launch_bounds__(SCAN_THREADS) void esn_scan(
    const float* __restrict__ u,      // (B, T, I)
    const float* __restrict__ Win,    // (R, I)
    const float* __restrict__ W,      // (R, R)
    const float* __restrict__ bias,   // (R)
    float* __restrict__ states,       // (T+1, B, R) workspace
    unsigned* __restrict__ flags)     // (SCAN_BLOCKS) step counters
{
    __shared__ float Wl[ROWS_PER_BLK * RDIM];   // 64 KB

    const int tid  = threadIdx.x;
    const int bid  = blockIdx.x;
    const int r0   = bid * ROWS_PER_BLK;

    // ---- stage W slice (contiguous 64 KB) into LDS (read-only input: cached ok)
    {
        const float4* src = (const float4*)(W + (size_t)r0 * RDIM);
        float4* dst = (float4*)Wl;
        #pragma unroll
        for (int idx = 0; idx < (ROWS_PER_BLK * RDIM) / 4 / SCAN_THREADS; ++idx)
            dst[idx * SCAN_THREADS + tid] = src[idx * SCAN_THREADS + tid];
    }

    const int wave = tid >> 6;
    const int lane = tid & 63;
    const int bb   = lane & 3;
    const int ks   = lane >> 2;          // 0..15
    const int b    = wave * 4 + bb;      // 0..31
    const int k0   = ks * 4;             // 0..60

    float my_bias = 0.0f;
    if (lane < 32) my_bias = bias[r0 + (lane >> 2)];
    const int bf = wave * 4 + (lane & 3);

    float acc[8];

    // u_proj partial for one timestep (read-only inputs: normal cached loads)
    auto u_part = [&](int t) {
        const float* ub = u + ((size_t)b * SEQ + t) * IDIM;
        #pragma unroll
        for (int j = 0; j < 4; ++j) {
            const int iu = k0 + 64 * j;
            float4 u4 = *(const float4*)(ub + iu);
            #pragma unroll
            for (int r = 0; r < 8; ++r) {
                float4 w4 = *(const float4*)(Win + (size_t)(r0 + r) * IDIM + iu);
                acc[r] += w4.x * u4.x + w4.y * u4.y + w4.z * u4.z + w4.w * u4.w;
            }
        }
    };

    __syncthreads();   // Wl ready

    #pragma unroll
    for (int r = 0; r < 8; ++r) acc[r] = 0.0f;
    u_part(0);

    for (int t = 0; t < SEQ; ++t) {
        const float* prev = states + (size_t)t * BATCH * RDIM;
        float* next = states + (size_t)(t + 1) * BATCH * RDIM;

        // ---- main recurrent dot via sc1 (L3-direct) state loads ----
        const float* sp = prev + (size_t)b * RDIM + k0;
        f4 sbuf[8];
        #pragma unroll
        for (int half = 0; half < 4; ++half) {
            load8_f4_sc1(sp + half * 512, sbuf);
            #pragma unroll
            for (int i = 0; i < 8; ++i) {
                f4 s4 = sbuf[i];
                const int kk = k0 + 64 * (half * 8 + i);
                #pragma unroll
                for (int r = 0; r < 8; ++r) {
                    f4 w4 = *(const f4*)(&Wl[r * RDIM + kk]);
                    acc[r] += w4[0] * s4[0] + w4[1] * s4[1]
                            + w4[2] * s4[2] + w4[3] * s4[3];
                }
            }
        }

        // hoist the prev-state re-read (sc1) so its L3 latency hides under the
        // shuffle-reduce below
        float so = 0.0f;
        if (lane < 32) {
            so = __hip_atomic_load(&prev[(size_t)bf * RDIM + r0 + (lane >> 2)],
                                   __ATOMIC_RELAXED, __HIP_MEMORY_SCOPE_AGENT);
        }

        // ---- reduce over the 16 k-slices (xor 4,8,16,32 keeps bb class) ----
        #pragma unroll
        for (int m = 4; m <= 32; m <<= 1) {
            #pragma unroll
            for (int r = 0; r < 8; ++r) acc[r] += __shfl_xor(acc[r], m, 64);
        }

        // ---- finalize: lanes 0..31 handle (bf, rr); store sc1 relaxed ----
        if (lane < 32) {
            const int rr = lane >> 2;
            float pre = acc[0];
            #pragma unroll
            for (int r = 1; r < 8; ++r) if (rr == r) pre = acc[r];
            pre += my_bias;
            float sn = (1.0f - LEAK) * so + LEAK * tanhf(pre);
            __hip_atomic_store(&next[(size_t)bf * RDIM + r0 + rr], sn,
                               __ATOMIC_RELAXED, __HIP_MEMORY_SCOPE_AGENT);
        }

        // per-wave: wait own sc1 stores acked at coherent point, then block sync
        asm volatile("s_waitcnt vmcnt(0)" ::: "memory");
        __syncthreads();
        if (tid == 0) {
            __hip_atomic_store(&flags[bid], (unsigned)(t + 1),
                               __ATOMIC_RELAXED, __HIP_MEMORY_SCOPE_AGENT);
        }

        // independent next-step u_proj work while flags propagate
        #pragma unroll
        for (int r = 0; r < 8; ++r) acc[r] = 0.0f;
        if (t + 1 < SEQ) u_part(t + 1);

        // fence-free barrier: each of 256 threads spins on one block's flag
        // with relaxed sc1 loads (no buffer_inv per poll)
        if (tid < SCAN_BLOCKS) {
            while (__hip_atomic_load(&flags[tid], __ATOMIC_RELAXED,
                                     __HIP_MEMORY_SCOPE_AGENT) < (unsigned)(t + 1)) {
                __builtin_amdgcn_s_sleep(1);
            }
        }
        __syncthreads();
    }
}

// ---------------------------------------------------------------------------
// readout: out[b][t][o] = sum_r states[t+1][b][r] * w_ro[o][r] + b_ro[o]
// ---------------------------------------------------------------------------
#define RO_THREADS 256
__global__ __launch_bounds__(RO_THREADS) void esn_readout(
    const float* __restrict__ states,   // (T+1, B, R); rows (t*32+b) start at slot 1
    const float* __restrict__ w_ro,     // (O, R)
    const float* __restrict__ b_ro,     // (O)
    float* __restrict__ out)            // (B, T, O)
{
    __shared__ float St[32][68];
    __shared__ float Wt[32][68];

    const int tid  = threadIdx.x;
    const int rb   = blockIdx.x >> 2;
    const int ob   = blockIdx.x & 3;
    const int row0 = rb * 64;
    const int o0   = ob * 64;
    const float* S = states + (size_t)BATCH * RDIM;   // skip slot 0

    const int lr = tid >> 3;          // 0..31
    const int lk = (tid & 7) * 4;     // 0..28
    const int tx = tid & 15;          // o quad
    const int ty = tid >> 4;          // row quad

    float acc[4][4] = {};

    for (int kt = 0; kt < RDIM; kt += 32) {
        float4 a0 = *(const float4*)(S + (size_t)(row0 + lr)      * RDIM + kt + lk);
        float4 a1 = *(const float4*)(S + (size_t)(row0 + 32 + lr) * RDIM + kt + lk);
        float4 w0 = *(const float4*)(w_ro + (size_t)(o0 + lr)      * RDIM + kt + lk);
        float4 w1 = *(const float4*)(w_ro + (size_t)(o0 + 32 + lr) * RDIM + kt + lk);
        __syncthreads();
        float av0[4] = {a0.x, a0.y, a0.z, a0.w};
        float av1[4] = {a1.x, a1.y, a1.z, a1.w};
        float wv0[4] = {w0.x, w0.y, w0.z, w0.w};
        float wv1[4] = {w1.x, w1.y, w1.z, w1.w};
        #pragma unroll
        for (int j = 0; j < 4; ++j) {
            St[lk + j][lr]      = av0[j];
            St[lk + j][32 + lr] = av1[j];
            Wt[lk + j][lr]      = wv0[j];
            Wt[lk + j][32 + lr] = wv1[j];
        }
        __syncthreads();
        #pragma unroll
        for (int k = 0; k < 32; ++k) {
            float4 a4 = *(const float4*)(&St[k][4 * ty]);
            float4 b4 = *(const float4*)(&Wt[k][4 * tx]);
            float av[4] = {a4.x, a4.y, a4.z, a4.w};
            float bv[4] = {b4.x, b4.y, b4.z, b4.w};
            #pragma unroll
            for (int ri = 0; ri < 4; ++ri)
                #pragma unroll
                for (int oi = 0; oi < 4; ++oi)
                    acc[ri][oi] += av[ri] * bv[oi];
        }
    }

    float4 br = *(const float4*)(b_ro + o0 + 4 * tx);
    float brv[4] = {br.x, br.y, br.z, br.w};
    #pragma unroll
    for (int ri = 0; ri < 4; ++ri) {
        int row = row0 + 4 * ty + ri;
        int tt  = row >> 5;
        int bbx = row & 31;
        float4 v;
        v.x = acc[ri][0] + brv[0];
        v.y = acc[ri][1] + brv[1];
        v.z = acc[ri][2] + brv[2];
        v.w = acc[ri][3] + brv[3];
        *(float4*)(out + ((size_t)bbx * SEQ + tt) * ODIM + o0 + 4 * tx) = v;
    }
}

// ---------------------------------------------------------------------------
extern "C" void kernel_launch(void* const* d_in, const int* in_sizes, int n_in,
                              void* d_out, int out_size, void* d_ws, size_t ws_size,
                              hipStream_t stream) {
    const float* u    = (const float*)d_in[0];
    const float* s0   = (const float*)d_in[1];
    const float* Win  = (const float*)d_in[2];
    const float* W    = (const float*)d_in[3];
    const float* bias = (const float*)d_in[4];
    const float* w_ro = (const float*)d_in[5];
    const float* b_ro = (const float*)d_in[6];
    float* out = (float*)d_out;

    const size_t states_elems = (size_t)(SEQ + 1) * BATCH * RDIM;
    const size_t states_bytes = states_elems * sizeof(float);
    const size_t need = states_bytes + SCAN_BLOCKS * sizeof(unsigned);
    if (ws_size < need) return;   // visible failure rather than OOB writes

    float* states = (float*)d_ws;
    unsigned* flags = (unsigned*)((char*)d_ws + states_bytes);

    esn_init<<<dim3(64), dim3(256), 0, stream>>>(s0, states, flags);

    void* args[] = { (void*)&u, (void*)&Win, (void*)&W, (void*)&bias,
                     (void*)&states, (void*)&flags };
    hipLaunchCooperativeKernel((const void*)esn_scan,
                               dim3(SCAN_BLOCKS), dim3(SCAN_THREADS),
                               args, 0, stream);

    esn_readout<<<dim3((SEQ * BATCH / 64) * (ODIM / 64)), dim3(RO_THREADS), 0, stream>>>(
        states, w_ro, b_ro, out);
}

// Round 3
// 34866.730 us; speedup vs baseline: 3.8109x; 3.8109x over previous
//
#include <hip/hip_runtime.h>
#include <math.h>

#define BATCH 32
#define SEQ   512
#define IDIM  256
#define RDIM  2048
#define ODIM  256
#define LEAK  0.3f

#define SCAN_BLOCKS  256
#define SCAN_THREADS 512
#define ROWS_PER_BLK 8   // RDIM / SCAN_BLOCKS

typedef float f4 __attribute__((ext_vector_type(4)));

__device__ __forceinline__ unsigned ld_flag(const unsigned* p) {
    return __hip_atomic_load(p, __ATOMIC_RELAXED, __HIP_MEMORY_SCOPE_AGENT);
}
__device__ __forceinline__ void st_flag(unsigned* p, unsigned v) {
    __hip_atomic_store(p, v, __ATOMIC_RELAXED, __HIP_MEMORY_SCOPE_AGENT);
}

// ---------------------------------------------------------------------------
// init: copy initial state into states slot 0, zero flags region (incl. go)
// ---------------------------------------------------------------------------
__global__ void esn_init(const float* __restrict__ s0, float* __restrict__ states,
                         unsigned* __restrict__ flags) {
    int idx = blockIdx.x * blockDim.x + threadIdx.x;
    const int n4 = (BATCH * RDIM) / 4;
    if (idx < n4) {
        ((float4*)states)[idx] = ((const float4*)s0)[idx];
    }
    if (idx < 512) flags[idx] = 0u;
}

// ---------------------------------------------------------------------------
// persistent cooperative scan.
// Protocol (fence-free, no cache-maintenance ops):
//  - state slot t+1 addresses are written exactly once (sc1 write-through ->
//    coherent at MALL), and read (normal cached loads) only after barrier t+1.
//    A line can enter an L2 only post-barrier => never stale. No buffer_inv.
//  - flags/go are the only sc1-read lines; pollers: 64 lanes (block 0) + 255
//    single threads (go line), s_sleep-backed.
// Compute mapping: wave w -> batches 4w..4w+3 (in registers, 4x W reuse);
// lane l -> k in {4l + 256c, c=0..7}; coalesced global s, 1KB/wave ds_read.
// ---------------------------------------------------------------------------
__global__ __launch_bounds__(SCAN_THREADS, 2) void esn_scan(
    const float* __restrict__ u,      // (B, T, I)
    const float* __restrict__ Win,    // (R, I)
    const float* __restrict__ W,      // (R, R)
    const float* __restrict__ bias,   // (R)
    float* __restrict__ states,       // (T+1, B, R) workspace
    unsigned* __restrict__ flags)     // [0..255] per-block step; [320] = go
{
    __shared__ float Wl[ROWS_PER_BLK * RDIM];   // 64 KB

    const int tid  = threadIdx.x;
    const int bid  = blockIdx.x;
    const int r0   = bid * ROWS_PER_BLK;
    unsigned* go   = flags + 320;

    // ---- stage W slice (contiguous 64 KB) into LDS ----
    {
        const float4* src = (const float4*)(W + (size_t)r0 * RDIM);
        float4* dst = (float4*)Wl;
        #pragma unroll
        for (int i = 0; i < (ROWS_PER_BLK * RDIM) / 4 / SCAN_THREADS; ++i)
            dst[i * SCAN_THREADS + tid] = src[i * SCAN_THREADS + tid];
    }

    const int wave = tid >> 6;           // 0..7
    const int lane = tid & 63;           // 64-way k-split
    const int b0   = wave * 4;           // batches b0..b0+3
    const int kb   = lane * 4;           // k base within each 256-chunk

    float my_bias = (lane < 32) ? bias[r0 + (lane >> 2)] : 0.0f;
    const int bf = b0 + (lane & 3);      // finalize batch (lanes<32)
    const int rr = lane >> 2;            // finalize row   (lanes<32)

    float acc[8][4];                     // [row][batch]

    auto u_part = [&](int t) {
        f4 u4[4];
        #pragma unroll
        for (int bb = 0; bb < 4; ++bb)
            u4[bb] = *(const f4*)(u + ((size_t)(b0 + bb) * SEQ + t) * IDIM + kb);
        #pragma unroll
        for (int r = 0; r < 8; ++r) {
            f4 w4 = *(const f4*)(Win + (size_t)(r0 + r) * IDIM + kb);
            #pragma unroll
            for (int bb = 0; bb < 4; ++bb)
                acc[r][bb] += w4[0] * u4[bb][0] + w4[1] * u4[bb][1]
                            + w4[2] * u4[bb][2] + w4[3] * u4[bb][3];
        }
    };

    __syncthreads();   // Wl ready

    #pragma unroll
    for (int r = 0; r < 8; ++r)
        #pragma unroll
        for (int bb = 0; bb < 4; ++bb) acc[r][bb] = 0.0f;
    u_part(0);

    for (int t = 0; t < SEQ; ++t) {
        const float* prev = states + (size_t)t * (BATCH * RDIM);
        float* next = states + (size_t)(t + 1) * (BATCH * RDIM);

        // ---- recurrent dot, two k-halves (VGPR control), normal cached loads
        for (int half = 0; half < 2; ++half) {
            f4 s4[4][4];
            #pragma unroll
            for (int c = 0; c < 4; ++c)
                #pragma unroll
                for (int bb = 0; bb < 4; ++bb)
                    s4[c][bb] = *(const f4*)(prev + (size_t)(b0 + bb) * RDIM
                                             + 256 * (half * 4 + c) + kb);
            #pragma unroll
            for (int c = 0; c < 4; ++c)
                #pragma unroll
                for (int r = 0; r < 8; ++r) {
                    f4 w4 = *(const f4*)(&Wl[r * RDIM + 256 * (half * 4 + c) + kb]);
                    #pragma unroll
                    for (int bb = 0; bb < 4; ++bb)
                        acc[r][bb] += w4[0] * s4[c][bb][0] + w4[1] * s4[c][bb][1]
                                    + w4[2] * s4[c][bb][2] + w4[3] * s4[c][bb][3];
                }
        }

        // hoist prev-state re-read (normal load, L1-warm) under the reduction
        float so = 0.0f;
        if (lane < 32) so = prev[(size_t)bf * RDIM + r0 + rr];

        // ---- reduce 32 accs over 64 lanes ----
        // stages xor 1,2 (DPP quad ops): quad-sums of all 32 values
        #pragma unroll
        for (int r = 0; r < 8; ++r)
            #pragma unroll
            for (int bb = 0; bb < 4; ++bb) {
                float v = acc[r][bb];
                v += __shfl_xor(v, 1, 64);
                v += __shfl_xor(v, 2, 64);
                acc[r][bb] = v;
            }
        // compact: lane keeps batch q = lane&3, then reduce over 16 quads
        const int q = lane & 3;
        float v8[8];
        #pragma unroll
        for (int r = 0; r < 8; ++r) {
            float a01 = (q & 1) ? acc[r][1] : acc[r][0];
            float a23 = (q & 1) ? acc[r][3] : acc[r][2];
            float v   = (q & 2) ? a23 : a01;
            v += __shfl_xor(v, 4, 64);
            v += __shfl_xor(v, 8, 64);
            v += __shfl_xor(v, 16, 64);
            v += __shfl_xor(v, 32, 64);
            v8[r] = v;
        }

        // ---- finalize: lanes 0..31 -> (bf, r0+rr); sc1 write-through store
        if (lane < 32) {
            float pre = v8[0];
            #pragma unroll
            for (int r = 1; r < 8; ++r) if (rr == r) pre = v8[r];
            pre += my_bias;
            float sn = (1.0f - LEAK) * so + LEAK * tanhf(pre);
            __hip_atomic_store(&next[(size_t)bf * RDIM + r0 + rr], sn,
                               __ATOMIC_RELAXED, __HIP_MEMORY_SCOPE_AGENT);
        }

        // own stores acked at coherent point, then block-wide flag
        asm volatile("s_waitcnt vmcnt(0)" ::: "memory");
        __syncthreads();
        if (tid == 0) st_flag(&flags[bid], (unsigned)(t + 1));
        asm volatile("" ::: "memory");   // don't sink the flag store below polls

        // overlapped independent work: u_proj(t+1)
        #pragma unroll
        for (int r = 0; r < 8; ++r)
            #pragma unroll
            for (int bb = 0; bb < 4; ++bb) acc[r][bb] = 0.0f;
        if (t + 1 < SEQ) u_part(t + 1);

        // ---- barrier: block0/wave0 aggregates flags -> go; others poll go
        const unsigned tp = (unsigned)(t + 1);
        if (bid == 0) {
            if (tid < 64) {
                for (;;) {
                    unsigned f0 = ld_flag(&flags[tid]);
                    unsigned f1 = ld_flag(&flags[64 + tid]);
                    unsigned f2 = ld_flag(&flags[128 + tid]);
                    unsigned f3 = ld_flag(&flags[192 + tid]);
                    bool ok = (f0 >= tp) & (f1 >= tp) & (f2 >= tp) & (f3 >= tp);
                    if (__all(ok)) break;
                    __builtin_amdgcn_s_sleep(2);
                }
                asm volatile("" ::: "memory");
                if (tid == 0) st_flag(go, tp);
            }
        } else {
            if (tid == 0) {
                while (ld_flag(go) < tp) __builtin_amdgcn_s_sleep(2);
            }
        }
        __syncthreads();
    }
}

// ---------------------------------------------------------------------------
// readout: out[b][t][o] = sum_r states[t+1][b][r] * w_ro[o][r] + b_ro[o]
// ---------------------------------------------------------------------------
#define RO_THREADS 256
__global__ __launch_bounds__(RO_THREADS) void esn_readout(
    const float* __restrict__ states,   // (T+1, B, R); rows (t*32+b) start at slot 1
    const float* __restrict__ w_ro,     // (O, R)
    const float* __restrict__ b_ro,     // (O)
    float* __restrict__ out)            // (B, T, O)
{
    __shared__ float St[32][68];
    __shared__ float Wt[32][68];

    const int tid  = threadIdx.x;
    const int rb   = blockIdx.x >> 2;
    const int ob   = blockIdx.x & 3;
    const int row0 = rb * 64;
    const int o0   = ob * 64;
    const float* S = states + (size_t)BATCH * RDIM;   // skip slot 0

    const int lr = tid >> 3;          // 0..31
    const int lk = (tid & 7) * 4;     // 0..28
    const int tx = tid & 15;          // o quad
    const int ty = tid >> 4;          // row quad

    float acc[4][4] = {};

    for (int kt = 0; kt < RDIM; kt += 32) {
        float4 a0 = *(const float4*)(S + (size_t)(row0 + lr)      * RDIM + kt + lk);
        float4 a1 = *(const float4*)(S + (size_t)(row0 + 32 + lr) * RDIM + kt + lk);
        float4 w0 = *(const float4*)(w_ro + (size_t)(o0 + lr)      * RDIM + kt + lk);
        float4 w1 = *(const float4*)(w_ro + (size_t)(o0 + 32 + lr) * RDIM + kt + lk);
        __syncthreads();
        float av0[4] = {a0.x, a0.y, a0.z, a0.w};
        float av1[4] = {a1.x, a1.y, a1.z, a1.w};
        float wv0[4] = {w0.x, w0.y, w0.z, w0.w};
        float wv1[4] = {w1.x, w1.y, w1.z, w1.w};
        #pragma unroll
        for (int j = 0; j < 4; ++j) {
            St[lk + j][lr]      = av0[j];
            St[lk + j][32 + lr] = av1[j];
            Wt[lk + j][lr]      = wv0[j];
            Wt[lk + j][32 + lr] = wv1[j];
        }
        __syncthreads();
        #pragma unroll
        for (int k = 0; k < 32; ++k) {
            float4 a4 = *(const float4*)(&St[k][4 * ty]);
            float4 b4 = *(const float4*)(&Wt[k][4 * tx]);
            float av[4] = {a4.x, a4.y, a4.z, a4.w};
            float bv[4] = {b4.x, b4.y, b4.z, b4.w};
            #pragma unroll
            for (int ri = 0; ri < 4; ++ri)
                #pragma unroll
                for (int oi = 0; oi < 4; ++oi)
                    acc[ri][oi] += av[ri] * bv[oi];
        }
    }

    float4 br = *(const float4*)(b_ro + o0 + 4 * tx);
    float brv[4] = {br.x, br.y, br.z, br.w};
    #pragma unroll
    for (int ri = 0; ri < 4; ++ri) {
        int row = row0 + 4 * ty + ri;
        int tt  = row >> 5;
        int bbx = row & 31;
        float4 v;
        v.x = acc[ri][0] + brv[0];
        v.y = acc[ri][1] + brv[1];
        v.z = acc[ri][2] + brv[2];
        v.w = acc[ri][3] + brv[3];
        *(float4*)(out + ((size_t)bbx * SEQ + tt) * ODIM + o0 + 4 * tx) = v;
    }
}

// ---------------------------------------------------------------------------
extern "C" void kernel_launch(void* const* d_in, const int* in_sizes, int n_in,
                              void* d_out, int out_size, void* d_ws, size_t ws_size,
                              hipStream_t stream) {
    const float* u    = (const float*)d_in[0];
    const float* s0   = (const float*)d_in[1];
    const float* Win  = (const float*)d_in[2];
    const float* W    = (const float*)d_in[3];
    const float* bias = (const float*)d_in[4];
    const float* w_ro = (const float*)d_in[5];
    const float* b_ro = (const float*)d_in[6];
    float* out = (float*)d_out;

    const size_t states_elems = (size_t)(SEQ + 1) * BATCH * RDIM;
    const size_t states_bytes = states_elems * sizeof(float);
    const size_t need = states_bytes + 2048;
    if (ws_size < need) return;   // visible failure rather than OOB writes

    float* states = (float*)d_ws;
    unsigned* flags = (unsigned*)((char*)d_ws + states_bytes);

    esn_init<<<dim3(64), dim3(256), 0, stream>>>(s0, states, flags);

    void* args[] = { (void*)&u, (void*)&Win, (void*)&W, (void*)&bias,
                     (void*)&states, (void*)&flags };
    hipLaunchCooperativeKernel((const void*)esn_scan,
                               dim3(SCAN_BLOCKS), dim3(SCAN_THREADS),
                               args, 0, stream);

    esn_readout<<<dim3((SEQ * BATCH / 64) * (ODIM / 64)), dim3(RO_THREADS), 0, stream>>>(
        states, w_ro, b_ro, out);
}

// Round 4
// 8802.568 us; speedup vs baseline: 15.0948x; 3.9610x over previous
//
#include <hip/hip_runtime.h>
#include <math.h>

#define BATCH 32
#define SEQ   512
#define IDIM  256
#define RDIM  2048
#define ODIM  256
#define LEAK  0.3f

#define SCAN_BLOCKS  256
#define SCAN_THREADS 512
#define ROWS_PER_BLK 8   // RDIM / SCAN_BLOCKS

typedef float f4 __attribute__((ext_vector_type(4)));

__device__ __forceinline__ unsigned ld_flag(const unsigned* p) {
    return __hip_atomic_load(p, __ATOMIC_RELAXED, __HIP_MEMORY_SCOPE_AGENT);
}
__device__ __forceinline__ void st_flag(unsigned* p, unsigned v) {
    __hip_atomic_store(p, v, __ATOMIC_RELAXED, __HIP_MEMORY_SCOPE_AGENT);
}

// ---------------------------------------------------------------------------
// init: copy initial state into states slot 0, zero flags region (incl. go)
// ---------------------------------------------------------------------------
__global__ void esn_init(const float* __restrict__ s0, float* __restrict__ states,
                         unsigned* __restrict__ flags) {
    int idx = blockIdx.x * blockDim.x + threadIdx.x;
    const int n4 = (BATCH * RDIM) / 4;
    if (idx < n4) {
        ((float4*)states)[idx] = ((const float4*)s0)[idx];
    }
    if (idx < 512) flags[idx] = 0u;
}

// ---------------------------------------------------------------------------
// persistent cooperative scan.
// Protocol (fence-free, no cache-maintenance ops) - unchanged from round 3:
//  - state slot t+1 addresses are written exactly once (sc1 write-through ->
//    coherent at MALL) and read (normal cached loads) only after barrier t+1.
//    A line enters an L2 only post-barrier => never stale. No buffer_inv.
//  - flags/go are the only sc1-polled lines.
// Round-4 change: chunked k-loop (4 f4 live + 4 f4 prefetch) instead of a
// 16-f4 preload -> ~80 live VGPRs, no scratch spills (round 3: 95 GB of
// spill write-back was 95% of the step time).
// ---------------------------------------------------------------------------
__global__ __launch_bounds__(SCAN_THREADS) void esn_scan(
    const float* __restrict__ u,      // (B, T, I)
    const float* __restrict__ Win,    // (R, I)
    const float* __restrict__ W,      // (R, R)
    const float* __restrict__ bias,   // (R)
    float* __restrict__ states,       // (T+1, B, R) workspace
    unsigned* __restrict__ flags)     // [0..255] per-block step; [320] = go
{
    __shared__ float Wl[ROWS_PER_BLK * RDIM];   // 64 KB

    const int tid  = threadIdx.x;
    const int bid  = blockIdx.x;
    const int r0   = bid * ROWS_PER_BLK;
    unsigned* go   = flags + 320;

    // ---- stage W slice (contiguous 64 KB) into LDS ----
    {
        const float4* src = (const float4*)(W + (size_t)r0 * RDIM);
        float4* dst = (float4*)Wl;
        #pragma unroll
        for (int i = 0; i < (ROWS_PER_BLK * RDIM) / 4 / SCAN_THREADS; ++i)
            dst[i * SCAN_THREADS + tid] = src[i * SCAN_THREADS + tid];
    }

    const int wave = tid >> 6;           // 0..7
    const int lane = tid & 63;           // 64-way k-split
    const int b0   = wave * 4;           // batches b0..b0+3
    const int kb   = lane * 4;           // k base within each 256-chunk

    float my_bias = (lane < 32) ? bias[r0 + (lane >> 2)] : 0.0f;
    const int bf = b0 + (lane & 3);      // finalize batch (lanes<32)
    const int rr = lane >> 2;            // finalize row   (lanes<32)

    float acc[8][4];                     // [row][batch]

    auto u_part = [&](int t) {
        f4 u4[4];
        #pragma unroll
        for (int bb = 0; bb < 4; ++bb)
            u4[bb] = *(const f4*)(u + ((size_t)(b0 + bb) * SEQ + t) * IDIM + kb);
        #pragma unroll
        for (int r = 0; r < 8; ++r) {
            f4 w4 = *(const f4*)(Win + (size_t)(r0 + r) * IDIM + kb);
            #pragma unroll
            for (int bb = 0; bb < 4; ++bb)
                acc[r][bb] += w4[0] * u4[bb][0] + w4[1] * u4[bb][1]
                            + w4[2] * u4[bb][2] + w4[3] * u4[bb][3];
        }
    };

    __syncthreads();   // Wl ready

    #pragma unroll
    for (int r = 0; r < 8; ++r)
        #pragma unroll
        for (int bb = 0; bb < 4; ++bb) acc[r][bb] = 0.0f;
    u_part(0);

    for (int t = 0; t < SEQ; ++t) {
        const float* prev = states + (size_t)t * (BATCH * RDIM);
        float* next = states + (size_t)(t + 1) * (BATCH * RDIM);

        // ---- recurrent dot: 8 chunks of 256 k, 4-batch regs + prefetch ----
        {
            const float* sb = prev + kb;
            f4 s_cur[4], s_nxt[4];
            #pragma unroll
            for (int bb = 0; bb < 4; ++bb)
                s_cur[bb] = *(const f4*)(sb + (size_t)(b0 + bb) * RDIM);

            #pragma unroll 1
            for (int c = 0; c < 8; ++c) {
                if (c < 7) {
                    #pragma unroll
                    for (int bb = 0; bb < 4; ++bb)
                        s_nxt[bb] = *(const f4*)(sb + (size_t)(b0 + bb) * RDIM
                                                 + (c + 1) * 256);
                }
                const float* wl = &Wl[c * 256 + kb];
                #pragma unroll
                for (int r = 0; r < 8; ++r) {
                    f4 w4 = *(const f4*)(wl + r * RDIM);
                    #pragma unroll
                    for (int bb = 0; bb < 4; ++bb)
                        acc[r][bb] += w4[0] * s_cur[bb][0] + w4[1] * s_cur[bb][1]
                                    + w4[2] * s_cur[bb][2] + w4[3] * s_cur[bb][3];
                }
                #pragma unroll
                for (int bb = 0; bb < 4; ++bb) s_cur[bb] = s_nxt[bb];
            }
        }

        // hoist prev-state re-read (normal load, cache-warm) under reduction
        float so = 0.0f;
        if (lane < 32) so = prev[(size_t)bf * RDIM + r0 + rr];

        // ---- reduce 32 accs over 64 lanes (identical to round 3) ----
        #pragma unroll
        for (int r = 0; r < 8; ++r)
            #pragma unroll
            for (int bb = 0; bb < 4; ++bb) {
                float v = acc[r][bb];
                v += __shfl_xor(v, 1, 64);
                v += __shfl_xor(v, 2, 64);
                acc[r][bb] = v;
            }
        const int q = lane & 3;
        float v8[8];
        #pragma unroll
        for (int r = 0; r < 8; ++r) {
            float a01 = (q & 1) ? acc[r][1] : acc[r][0];
            float a23 = (q & 1) ? acc[r][3] : acc[r][2];
            float v   = (q & 2) ? a23 : a01;
            v += __shfl_xor(v, 4, 64);
            v += __shfl_xor(v, 8, 64);
            v += __shfl_xor(v, 16, 64);
            v += __shfl_xor(v, 32, 64);
            v8[r] = v;
        }

        // ---- finalize: lanes 0..31 -> (bf, r0+rr); sc1 write-through store
        if (lane < 32) {
            float pre = v8[0];
            #pragma unroll
            for (int r = 1; r < 8; ++r) if (rr == r) pre = v8[r];
            pre += my_bias;
            float sn = (1.0f - LEAK) * so + LEAK * tanhf(pre);
            __hip_atomic_store(&next[(size_t)bf * RDIM + r0 + rr], sn,
                               __ATOMIC_RELAXED, __HIP_MEMORY_SCOPE_AGENT);
        }

        // own stores acked at coherent point, then block-wide flag
        asm volatile("s_waitcnt vmcnt(0)" ::: "memory");
        __syncthreads();
        if (tid == 0) st_flag(&flags[bid], (unsigned)(t + 1));
        asm volatile("" ::: "memory");

        // overlapped independent work: u_proj(t+1)
        #pragma unroll
        for (int r = 0; r < 8; ++r)
            #pragma unroll
            for (int bb = 0; bb < 4; ++bb) acc[r][bb] = 0.0f;
        if (t + 1 < SEQ) u_part(t + 1);

        // ---- barrier: block0/wave0 aggregates flags -> go; others poll go
        const unsigned tp = (unsigned)(t + 1);
        if (bid == 0) {
            if (tid < 64) {
                for (;;) {
                    unsigned f0 = ld_flag(&flags[tid]);
                    unsigned f1 = ld_flag(&flags[64 + tid]);
                    unsigned f2 = ld_flag(&flags[128 + tid]);
                    unsigned f3 = ld_flag(&flags[192 + tid]);
                    bool ok = (f0 >= tp) & (f1 >= tp) & (f2 >= tp) & (f3 >= tp);
                    if (__all(ok)) break;
                    __builtin_amdgcn_s_sleep(2);
                }
                asm volatile("" ::: "memory");
                if (tid == 0) st_flag(go, tp);
            }
        } else {
            if (tid == 0) {
                while (ld_flag(go) < tp) __builtin_amdgcn_s_sleep(2);
            }
        }
        __syncthreads();
    }
}

// ---------------------------------------------------------------------------
// readout: out[b][t][o] = sum_r states[t+1][b][r] * w_ro[o][r] + b_ro[o]
// ---------------------------------------------------------------------------
#define RO_THREADS 256
__global__ __launch_bounds__(RO_THREADS) void esn_readout(
    const float* __restrict__ states,   // (T+1, B, R); rows (t*32+b) start at slot 1
    const float* __restrict__ w_ro,     // (O, R)
    const float* __restrict__ b_ro,     // (O)
    float* __restrict__ out)            // (B, T, O)
{
    __shared__ float St[32][68];
    __shared__ float Wt[32][68];

    const int tid  = threadIdx.x;
    const int rb   = blockIdx.x >> 2;
    const int ob   = blockIdx.x & 3;
    const int row0 = rb * 64;
    const int o0   = ob * 64;
    const float* S = states + (size_t)BATCH * RDIM;   // skip slot 0

    const int lr = tid >> 3;          // 0..31
    const int lk = (tid & 7) * 4;     // 0..28
    const int tx = tid & 15;          // o quad
    const int ty = tid >> 4;          // row quad

    float acc[4][4] = {};

    for (int kt = 0; kt < RDIM; kt += 32) {
        float4 a0 = *(const float4*)(S + (size_t)(row0 + lr)      * RDIM + kt + lk);
        float4 a1 = *(const float4*)(S + (size_t)(row0 + 32 + lr) * RDIM + kt + lk);
        float4 w0 = *(const float4*)(w_ro + (size_t)(o0 + lr)      * RDIM + kt + lk);
        float4 w1 = *(const float4*)(w_ro + (size_t)(o0 + 32 + lr) * RDIM + kt + lk);
        __syncthreads();
        float av0[4] = {a0.x, a0.y, a0.z, a0.w};
        float av1[4] = {a1.x, a1.y, a1.z, a1.w};
        float wv0[4] = {w0.x, w0.y, w0.z, w0.w};
        float wv1[4] = {w1.x, w1.y, w1.z, w1.w};
        #pragma unroll
        for (int j = 0; j < 4; ++j) {
            St[lk + j][lr]      = av0[j];
            St[lk + j][32 + lr] = av1[j];
            Wt[lk + j][lr]      = wv0[j];
            Wt[lk + j][32 + lr] = wv1[j];
        }
        __syncthreads();
        #pragma unroll
        for (int k = 0; k < 32; ++k) {
            float4 a4 = *(const float4*)(&St[k][4 * ty]);
            float4 b4 = *(const float4*)(&Wt[k][4 * tx]);
            float av[4] = {a4.x, a4.y, a4.z, a4.w};
            float bv[4] = {b4.x, b4.y, b4.z, b4.w};
            #pragma unroll
            for (int ri = 0; ri < 4; ++ri)
                #pragma unroll
                for (int oi = 0; oi < 4; ++oi)
                    acc[ri][oi] += av[ri] * bv[oi];
        }
    }

    float4 br = *(const float4*)(b_ro + o0 + 4 * tx);
    float brv[4] = {br.x, br.y, br.z, br.w};
    #pragma unroll
    for (int ri = 0; ri < 4; ++ri) {
        int row = row0 + 4 * ty + ri;
        int tt  = row >> 5;
        int bbx = row & 31;
        float4 v;
        v.x = acc[ri][0] + brv[0];
        v.y = acc[ri][1] + brv[1];
        v.z = acc[ri][2] + brv[2];
        v.w = acc[ri][3] + brv[3];
        *(float4*)(out + ((size_t)bbx * SEQ + tt) * ODIM + o0 + 4 * tx) = v;
    }
}

// ---------------------------------------------------------------------------
extern "C" void kernel_launch(void* const* d_in, const int* in_sizes, int n_in,
                              void* d_out, int out_size, void* d_ws, size_t ws_size,
                              hipStream_t stream) {
    const float* u    = (const float*)d_in[0];
    const float* s0   = (const float*)d_in[1];
    const float* Win  = (const float*)d_in[2];
    const float* W    = (const float*)d_in[3];
    const float* bias = (const float*)d_in[4];
    const float* w_ro = (const float*)d_in[5];
    const float* b_ro = (const float*)d_in[6];
    float* out = (float*)d_out;

    const size_t states_elems = (size_t)(SEQ + 1) * BATCH * RDIM;
    const size_t states_bytes = states_elems * sizeof(float);
    const size_t need = states_bytes + 2048;
    if (ws_size < need) return;   // visible failure rather than OOB writes

    float* states = (float*)d_ws;
    unsigned* flags = (unsigned*)((char*)d_ws + states_bytes);

    esn_init<<<dim3(64), dim3(256), 0, stream>>>(s0, states, flags);

    void* args[] = { (void*)&u, (void*)&Win, (void*)&W, (void*)&bias,
                     (void*)&states, (void*)&flags };
    hipLaunchCooperativeKernel((const void*)esn_scan,
                               dim3(SCAN_BLOCKS), dim3(SCAN_THREADS),
                               args, 0, stream);

    esn_readout<<<dim3((SEQ * BATCH / 64) * (ODIM / 64)), dim3(RO_THREADS), 0, stream>>>(
        states, w_ro, b_ro, out);
}